// Round 1
// baseline (1740.166 us; speedup 1.0000x reference)
//
#include <hip/hip_runtime.h>

// ---------------------------------------------------------------------------
// NeuralCA fused step: x (4,16,224,224) fp32, 40 steps of
//   p = conv3x3(x, Wp)  [16->48]          (folded into W_eff = W1 @ Wp, K=144)
//   h1 = relu(W_eff * im2col(x) + b1)     [->128]
//   h2 = relu(W2 h1 + b2)                 [->128]
//   dx = W3 h2                            [->16]
//   x  = clamp(x + dx, 0, 1)
// bf16 MFMA 16x16x32, fp32 master state (NHWC) + bf16 shadow (NHWC).
// ---------------------------------------------------------------------------

typedef __attribute__((ext_vector_type(8))) short short8;
typedef __attribute__((ext_vector_type(4))) float float4v;

#define MFMA16(a, b, c) __builtin_amdgcn_mfma_f32_16x16x32_bf16((a), (b), (c), 0, 0, 0)

__device__ __forceinline__ short f2bf(float f) {
  unsigned u = __builtin_bit_cast(unsigned, f);
  u = (u + 0x7fffu + ((u >> 16) & 1u)) >> 16;   // RNE
  return (short)u;
}

__device__ __forceinline__ void async16(const void* g, void* l) {
  // global -> LDS direct, 16B/lane; LDS dest = uniform base + lane*16
  __builtin_amdgcn_global_load_lds((const __attribute__((address_space(1))) void*)g,
                                   (__attribute__((address_space(3))) void*)l,
                                   16, 0, 0);
}

// ---- workspace layout (bytes) ----
// WE   [128][168] bf16 : 43008     (W_eff^T, K padded 144->160->168, zeros)
// W2   [128][136] bf16 : 34816     (W2^T, K sigma-permuted, padded 128->136)
// W3   [ 16][136] bf16 : 5120      (W3^T, K sigma-permuted, padded; tail zero)
// b1p  [128] f32       : 512       (sigma-permuted bias)
// b2p  [128] f32       : 512
// X32[2] NHWC f32      : 2 x 12845056
// X16[2] NHWC bf16     : 2 x 6422528
#define WS_WE    0
#define WS_W2    43008
#define WS_W3    77824
#define WS_B1    82944
#define WS_B2    83456
#define WS_X32A  83968
#define WS_X32B  12929024
#define WS_X16A  25774080
#define WS_X16B  32196608

// ---------------------------------------------------------------------------
__global__ void prep_x(const float* __restrict__ x, float* __restrict__ x32,
                       short* __restrict__ x16) {
  int i = blockIdx.x * 256 + threadIdx.x;          // exactly 3211264 threads
  int w = i % 224;
  int h = (i / 224) % 224;
  int c = (i / 50176) & 15;
  int bb = i / 802816;
  float v = x[i];
  int o = ((bb * 224 + h) * 224 + w) * 16 + c;     // NHWC
  x32[o] = v;
  x16[o] = f2bf(v);
}

// sigma: stored position p holds channel chan(p) = 16*(p&7) + (p>>3)
__global__ void prep_w(const float* __restrict__ wp, const float* __restrict__ w1,
                       const float* __restrict__ b1, const float* __restrict__ w2,
                       const float* __restrict__ b2, const float* __restrict__ w3,
                       short* __restrict__ wE, short* __restrict__ w2t,
                       short* __restrict__ w3t, float* __restrict__ b1p,
                       float* __restrict__ b2p) {
  int i = blockIdx.x * 256 + threadIdx.x;          // exactly 41728 threads
  if (i < 21504) {                                  // W_eff^T [o=128][k=168]
    int o = i / 168, k = i % 168;
    float v = 0.f;
    if (k < 144) {
      int off = k >> 4, c = k & 15;                 // k = offset*16 + c
      for (int c3 = 0; c3 < 48; ++c3)
        v += w1[o * 48 + c3] * wp[c3 * 144 + c * 9 + off];
    }
    wE[i] = f2bf(v);
  } else if (i < 38912) {                           // W2^T perm [n=128][kk=136]
    int j = i - 21504;
    int n = j / 136, kk = j % 136;
    float v = 0.f;
    if (kk < 128) { int ch = 16 * (kk & 7) + (kk >> 3); v = w2[n * 128 + ch]; }
    w2t[j] = f2bf(v);
  } else if (i < 41472) {                           // W3^T perm, padded to 2560
    int j = i - 38912;
    float v = 0.f;
    if (j < 2176) {
      int n = j / 136, kk = j % 136;
      if (kk < 128) { int ch = 16 * (kk & 7) + (kk >> 3); v = w3[n * 128 + ch]; }
    }
    w3t[j] = f2bf(v);
  } else if (i < 41600) {
    int p = i - 41472;
    b1p[p] = b1[16 * (p & 7) + (p >> 3)];
  } else {
    int p = i - 41600;
    b2p[p] = b2[16 * (p & 7) + (p >> 3)];
  }
}

// ---------------------------------------------------------------------------
// One CA step. Block = 4 image rows of one batch; 256 threads = 4 waves.
// Wave w owns M-tiles {w + 4i : i=0..13} of the 56 16-pixel tiles, processed
// as 7 pairs so B-fragments are reused across 2 M-tiles.
template <bool LAST>
__global__ __launch_bounds__(256, 1) void ca_step(
    const short* __restrict__ wEg, const short* __restrict__ w2g,
    const short* __restrict__ w3g, const float* __restrict__ b1p,
    const float* __restrict__ b2p, const float* __restrict__ xs32,
    const short* __restrict__ xs16, float* __restrict__ xd32,
    short* __restrict__ xd16, float* __restrict__ dout) {
  __shared__ short sWE[128 * 168];    // 43008 B
  __shared__ short sW2[128 * 136];    // 34816 B
  __shared__ short sW3[2560];         //  5120 B
  __shared__ short sXH[6 * 3616];     // 43392 B  halo: 6 rows x 226 cols x 16ch
  __shared__ short sSCR[4 * 4352];    // 34816 B  per-wave h scratch [32][136]
  // total 161152 B (<= 163840)

  const int tid = threadIdx.x;
  const int lane = tid & 63;
  const int wv = tid >> 6;
  const int c16 = lane & 15;
  const int q = lane >> 4;
  const int q8 = q * 8;
  const int qh = q >> 1;
  const int c0 = (q & 1) * 8;

  const int blk = blockIdx.x;          // 224 blocks = 4 batches x 56 rowgroups
  const int b = blk / 56;
  const int h0 = (blk % 56) * 4;

  // ---- stage weights: 81 x 1KB chunks ----
  for (int t = wv; t < 81; t += 4) {
    const char* g;
    char* l;
    if (t < 42)      { g = (const char*)wEg + t * 1024;        l = (char*)sWE + t * 1024; }
    else if (t < 76) { g = (const char*)w2g + (t - 42) * 1024; l = (char*)sW2 + (t - 42) * 1024; }
    else             { g = (const char*)w3g + (t - 76) * 1024; l = (char*)sW3 + (t - 76) * 1024; }
    async16(g + lane * 16, l);
  }
  // ---- stage halo: 6 rows x 7 chunks (1KB each); OOB rows -> zeros ----
  const short8 z8 = {0, 0, 0, 0, 0, 0, 0, 0};
  for (int t = wv; t < 42; t += 4) {
    int hr = t / 7, ck = t % 7;
    int hh = h0 - 1 + hr;
    char* l = (char*)sXH + hr * 7232 + 32 + ck * 1024;  // col 0 = image col -1
    if (hh >= 0 && hh < 224) {
      const char* g = (const char*)xs16 + ((size_t)(b * 224 + hh) * 224) * 32 + ck * 1024;
      async16(g + lane * 16, l);
    } else {
      *(short8*)(l + lane * 16) = z8;
    }
  }
  // zero edge columns (image col -1 and 224) for all 6 rows
  if (tid < 24) {
    int hr = tid >> 2, wch = tid & 3;
    int colb = (wch < 2) ? 0 : 225;
    *(short8*)((char*)sXH + hr * 7232 + colb * 32 + (wch & 1) * 16) = z8;
  }

  // per-lane biases: channels {16t + c16} live at p = c16*8 + t (contiguous)
  const float4v bA1 = *(const float4v*)(b1p + c16 * 8);
  const float4v bB1 = *(const float4v*)(b1p + c16 * 8 + 4);
  const float4v bA2 = *(const float4v*)(b2p + c16 * 8);
  const float4v bB2 = *(const float4v*)(b2p + c16 * 8 + 4);

  __syncthreads();

  short* scr = sSCR + wv * 4352;

  for (int j = 0; j < 7; ++j) {
    const int t1 = wv + 8 * j, t2 = t1 + 4;
    const int rr1 = t1 / 14, cb1 = (t1 % 14) * 16;
    const int rr2 = t2 / 14, cb2 = (t2 % 14) * 16;
    const int hbase1 = (rr1 * 226 + cb1) * 16;
    const int hbase2 = (rr2 * 226 + cb2) * 16;

    // ---- G1: [2x16 px] x [K=160] x [N=128]  (im2col conv+MLP1 fused) ----
    float4v acc1[2][8];
#pragma unroll
    for (int tt = 0; tt < 2; ++tt)
#pragma unroll
      for (int nt = 0; nt < 8; ++nt) acc1[tt][nt] = (float4v){0.f, 0.f, 0.f, 0.f};

#pragma unroll
    for (int kc = 0; kc < 5; ++kc) {
      int off = kc * 2 + qh;
      if (off > 8) off = 8;            // K 144..159 hits zero rows of W_eff
      int dy = (off * 11) >> 5;        // off/3 for off in [0,8]
      int dx = off - dy * 3;
      const int aoff = (dy * 226 + dx + c16) * 16 + c0;
      short8 a1 = *(const short8*)(sXH + hbase1 + aoff);
      short8 a2 = *(const short8*)(sXH + hbase2 + aoff);
#pragma unroll
      for (int nt = 0; nt < 8; ++nt) {
        short8 bf = *(const short8*)(sWE + (nt * 16 + c16) * 168 + kc * 32 + q8);
        acc1[0][nt] = MFMA16(a1, bf, acc1[0][nt]);
        acc1[1][nt] = MFMA16(a2, bf, acc1[1][nt]);
      }
    }
    // h1 = relu(acc1 + b1) -> bf16, packed b128 store (sigma layout)
#pragma unroll
    for (int tt = 0; tt < 2; ++tt) {
#pragma unroll
      for (int r = 0; r < 4; ++r) {
        short8 pk;
#pragma unroll
        for (int nt = 0; nt < 8; ++nt) {
          float v = acc1[tt][nt][r] + ((nt < 4) ? bA1[nt] : bB1[nt - 4]);
          pk[nt] = f2bf(fmaxf(v, 0.f));
        }
        *(short8*)(scr + (tt * 16 + q * 4 + r) * 136 + c16 * 8) = pk;
      }
    }

    // ---- G2: [2x16 px] x [K=128] x [N=128] ----
    float4v acc2[2][8];
#pragma unroll
    for (int tt = 0; tt < 2; ++tt)
#pragma unroll
      for (int nt = 0; nt < 8; ++nt) acc2[tt][nt] = (float4v){0.f, 0.f, 0.f, 0.f};

#pragma unroll
    for (int kc = 0; kc < 4; ++kc) {
      short8 a1 = *(const short8*)(scr + c16 * 136 + kc * 32 + q8);
      short8 a2 = *(const short8*)(scr + (16 + c16) * 136 + kc * 32 + q8);
#pragma unroll
      for (int nt = 0; nt < 8; ++nt) {
        short8 bf = *(const short8*)(sW2 + (nt * 16 + c16) * 136 + kc * 32 + q8);
        acc2[0][nt] = MFMA16(a1, bf, acc2[0][nt]);
        acc2[1][nt] = MFMA16(a2, bf, acc2[1][nt]);
      }
    }
    // h2 = relu(acc2 + b2) -> scratch (overwrites h1; all reads done)
#pragma unroll
    for (int tt = 0; tt < 2; ++tt) {
#pragma unroll
      for (int r = 0; r < 4; ++r) {
        short8 pk;
#pragma unroll
        for (int nt = 0; nt < 8; ++nt) {
          float v = acc2[tt][nt][r] + ((nt < 4) ? bA2[nt] : bB2[nt - 4]);
          pk[nt] = f2bf(fmaxf(v, 0.f));
        }
        *(short8*)(scr + (tt * 16 + q * 4 + r) * 136 + c16 * 8) = pk;
      }
    }

    // ---- G3: [2x16 px] x [K=128] x [N=16] ----
    float4v acc3[2];
    acc3[0] = (float4v){0.f, 0.f, 0.f, 0.f};
    acc3[1] = (float4v){0.f, 0.f, 0.f, 0.f};
#pragma unroll
    for (int kc = 0; kc < 4; ++kc) {
      short8 a1 = *(const short8*)(scr + c16 * 136 + kc * 32 + q8);
      short8 a2 = *(const short8*)(scr + (16 + c16) * 136 + kc * 32 + q8);
      short8 bf = *(const short8*)(sW3 + c16 * 136 + kc * 32 + q8);
      acc3[0] = MFMA16(a1, bf, acc3[0]);
      acc3[1] = MFMA16(a2, bf, acc3[1]);
    }

    // ---- epilogue: x = clamp(x + dx, 0, 1) ----
#pragma unroll
    for (int tt = 0; tt < 2; ++tt) {
      const int rr = tt ? rr2 : rr1;
      const int cb = tt ? cb2 : cb1;
      const int hglob = h0 + rr;
#pragma unroll
      for (int r = 0; r < 4; ++r) {
        int col = cb + q * 4 + r;
        size_t pix = (size_t)(b * 224 + hglob) * 224 + col;
        float v = xs32[pix * 16 + c16] + acc3[tt][r];
        v = fminf(fmaxf(v, 0.f), 1.f);
        if (LAST) {
          dout[((size_t)(b * 16 + c16) * 224 + hglob) * 224 + col] = v;  // NCHW
        } else {
          xd32[pix * 16 + c16] = v;
          xd16[pix * 16 + c16] = f2bf(v);
        }
      }
    }
  }
}

// ---------------------------------------------------------------------------
extern "C" void kernel_launch(void* const* d_in, const int* in_sizes, int n_in,
                              void* d_out, int out_size, void* d_ws, size_t ws_size,
                              hipStream_t stream) {
  const float* x  = (const float*)d_in[0];
  const float* wp = (const float*)d_in[1];
  const float* w1 = (const float*)d_in[2];
  const float* b1 = (const float*)d_in[3];
  const float* w2 = (const float*)d_in[4];
  const float* b2 = (const float*)d_in[5];
  const float* w3 = (const float*)d_in[6];
  // d_in[7] = steps (40, fixed by setup)

  char* ws = (char*)d_ws;
  short* wEg = (short*)(ws + WS_WE);
  short* w2g = (short*)(ws + WS_W2);
  short* w3g = (short*)(ws + WS_W3);
  float* b1p = (float*)(ws + WS_B1);
  float* b2p = (float*)(ws + WS_B2);
  float* X32[2] = {(float*)(ws + WS_X32A), (float*)(ws + WS_X32B)};
  short* X16[2] = {(short*)(ws + WS_X16A), (short*)(ws + WS_X16B)};

  prep_x<<<12544, 256, 0, stream>>>(x, X32[0], X16[0]);
  prep_w<<<163, 256, 0, stream>>>(wp, w1, b1, w2, b2, w3, wEg, w2g, w3g, b1p, b2p);

  for (int s = 0; s < 39; ++s) {
    int sb = s & 1;
    ca_step<false><<<224, 256, 0, stream>>>(wEg, w2g, w3g, b1p, b2p,
                                            X32[sb], X16[sb],
                                            X32[1 - sb], X16[1 - sb], nullptr);
  }
  ca_step<true><<<224, 256, 0, stream>>>(wEg, w2g, w3g, b1p, b2p,
                                         X32[1], X16[1],
                                         X32[0], X16[0], (float*)d_out);
}

// Round 2
// 1146.337 us; speedup vs baseline: 1.5180x; 1.5180x over previous
//
#include <hip/hip_runtime.h>

// ---------------------------------------------------------------------------
// NeuralCA fused step, wave-specialized:
//   waves 0-3 (G1):  h1 = relu(W_eff * im2col(x) + b1)   W_eff regs (160 VGPR)
//   waves 4-7 (G23): h2 = relu(W2 h1 + b2); dx = W3 h2;  W2/W3 regs (144 VGPR)
//   x = clamp(x + dx, 0, 1)
// h1 via double-buffered LDS mailbox, 1 barrier per pipeline iteration.
// bf16 MFMA 16x16x32, fp32 master state (NHWC) + bf16 shadow (NHWC).
// ---------------------------------------------------------------------------

typedef __attribute__((ext_vector_type(8))) short short8;
typedef __attribute__((ext_vector_type(4))) float float4v;

#define MFMA16(a, b, c) __builtin_amdgcn_mfma_f32_16x16x32_bf16((a), (b), (c), 0, 0, 0)

__device__ __forceinline__ short f2bf(float f) {
  unsigned u = __builtin_bit_cast(unsigned, f);
  return (short)((u + 0x8000u) >> 16);     // round-half-up (cheap, <=1/2 ulp off RNE)
}

__device__ __forceinline__ void async16(const void* g, void* l) {
  __builtin_amdgcn_global_load_lds((const __attribute__((address_space(1))) void*)g,
                                   (__attribute__((address_space(3))) void*)l,
                                   16, 0, 0);
}

// ---- workspace layout (bytes) ----
#define WS_WE    0          // W_eff^T [128][168] bf16 (K pad 144->168, zeros)
#define WS_W2    43008      // W2^T    [128][136] bf16 (K sigma-permuted)
#define WS_W3    77824      // W3^T    [ 16][136] bf16 (sigma-perm, pad to 2560)
#define WS_B1    82944      // b1 sigma-permuted f32 [128]
#define WS_B2    83456      // b2 sigma-permuted f32 [128]
#define WS_X32A  83968
#define WS_X32B  12929024
#define WS_X16A  25774080
#define WS_X16B  32196608

// ---------------------------------------------------------------------------
__global__ void prep_x(const float* __restrict__ x, float* __restrict__ x32,
                       short* __restrict__ x16) {
  int i = blockIdx.x * 256 + threadIdx.x;          // exactly 3211264 threads
  int w = i % 224;
  int h = (i / 224) % 224;
  int c = (i / 50176) & 15;
  int bb = i / 802816;
  float v = x[i];
  int o = ((bb * 224 + h) * 224 + w) * 16 + c;     // NHWC
  x32[o] = v;
  x16[o] = f2bf(v);
}

// sigma: stored position p holds channel chan(p) = 16*(p&7) + (p>>3)
__global__ void prep_w(const float* __restrict__ wp, const float* __restrict__ w1,
                       const float* __restrict__ b1, const float* __restrict__ w2,
                       const float* __restrict__ b2, const float* __restrict__ w3,
                       short* __restrict__ wE, short* __restrict__ w2t,
                       short* __restrict__ w3t, float* __restrict__ b1p,
                       float* __restrict__ b2p) {
  int i = blockIdx.x * 256 + threadIdx.x;          // exactly 41728 threads
  if (i < 21504) {                                  // W_eff^T [o=128][k=168]
    int o = i / 168, k = i % 168;
    float v = 0.f;
    if (k < 144) {
      int off = k >> 4, c = k & 15;                 // k = offset*16 + c
      for (int c3 = 0; c3 < 48; ++c3)
        v += w1[o * 48 + c3] * wp[c3 * 144 + c * 9 + off];
    }
    wE[i] = f2bf(v);
  } else if (i < 38912) {                           // W2^T perm [n=128][kk=136]
    int j = i - 21504;
    int n = j / 136, kk = j % 136;
    float v = 0.f;
    if (kk < 128) { int ch = 16 * (kk & 7) + (kk >> 3); v = w2[n * 128 + ch]; }
    w2t[j] = f2bf(v);
  } else if (i < 41472) {                           // W3^T perm, padded to 2560
    int j = i - 38912;
    float v = 0.f;
    if (j < 2176) {
      int n = j / 136, kk = j % 136;
      if (kk < 128) { int ch = 16 * (kk & 7) + (kk >> 3); v = w3[n * 128 + ch]; }
    }
    w3t[j] = f2bf(v);
  } else if (i < 41600) {
    int p = i - 41472;
    b1p[p] = b1[16 * (p & 7) + (p >> 3)];
  } else {
    int p = i - 41600;
    b2p[p] = b2[16 * (p & 7) + (p >> 3)];
  }
}

// ---------------------------------------------------------------------------
// One CA step. Block = 4 image rows of one batch, 512 threads = 8 waves.
// 56 M-tiles (16 px each) per block; G1 wave w makes tile 4j+w at iter j,
// G23 wave g consumes tile 4(j-1)+g at iter j. 15 iterations.
template <bool LAST>
__global__ __launch_bounds__(512, 2) void ca_step(
    const short* __restrict__ wEg, const short* __restrict__ w2g,
    const short* __restrict__ w3g, const float* __restrict__ b1p,
    const float* __restrict__ b2p, const float* __restrict__ xs32,
    const short* __restrict__ xs16, float* __restrict__ xd32,
    short* __restrict__ xd16, float* __restrict__ dout) {
  __shared__ short sXH[6 * 3616];       // 43392 B  halo: 6 rows x 226 x 16ch
  __shared__ short sBUF[2 * 4 * 2176];  // 34816 B  h1 mailbox, dbuf x 4 slots
  __shared__ short sH2[4 * 2176];       // 17408 B  per-G23-wave h2 scratch
  // total 95616 B -> 1 block/CU, 8 waves = 2/SIMD

  const int tid = threadIdx.x;
  const int lane = tid & 63;
  const int wv = tid >> 6;
  const int c16 = lane & 15;
  const int q = lane >> 4;
  const int q8 = q * 8;
  const int qh = q >> 1;
  const int c0 = (q & 1) * 8;

  const int blk = blockIdx.x;           // 224 blocks = 4 batches x 56 rowgroups
  const int b = blk / 56;
  const int h0 = (blk % 56) * 4;

  // ---- stage halo: 6 rows x 7 chunks (1KB each); OOB rows -> zeros ----
  const short8 z8 = {0, 0, 0, 0, 0, 0, 0, 0};
  for (int t = wv; t < 42; t += 8) {
    int hr = t / 7, ck = t % 7;
    int hh = h0 - 1 + hr;
    char* l = (char*)sXH + hr * 7232 + 32 + ck * 1024;  // col 0 = image col -1
    if (hh >= 0 && hh < 224) {
      const char* g = (const char*)xs16 + ((size_t)(b * 224 + hh) * 224) * 32 + ck * 1024;
      async16(g + lane * 16, l);
    } else {
      *(short8*)(l + lane * 16) = z8;
    }
  }
  if (tid < 24) {   // zero edge columns (image col -1 and 224) for all 6 rows
    int hr = tid >> 2, wch = tid & 3;
    int colb = (wch < 2) ? 0 : 225;
    *(short8*)((char*)sXH + hr * 7232 + colb * 32 + (wch & 1) * 16) = z8;
  }

  if (wv < 4) {
    // ================= G1 waves: conv3x3+MLP1 fused ======================
    short8 wf[5][8];                    // 160 VGPR: W_eff fragments
#pragma unroll
    for (int kc = 0; kc < 5; ++kc)
#pragma unroll
      for (int nt = 0; nt < 8; ++nt)
        wf[kc][nt] = *(const short8*)(wEg + (nt * 16 + c16) * 168 + kc * 32 + q8);
    const float4v bA = *(const float4v*)(b1p + c16 * 8);
    const float4v bB = *(const float4v*)(b1p + c16 * 8 + 4);

    __syncthreads();                    // halo ready

    for (int j = 0; j < 15; ++j) {
      if (j < 14) {
        const int t = 4 * j + wv;
        const int rr = t / 14, cb = (t % 14) * 16;
        const int hbase = (rr * 226 + cb) * 16;
        float4v acc[8];
#pragma unroll
        for (int nt = 0; nt < 8; ++nt) acc[nt] = (float4v){0.f, 0.f, 0.f, 0.f};
#pragma unroll
        for (int kc = 0; kc < 5; ++kc) {
          int off = kc * 2 + qh;
          if (off > 8) off = 8;         // K 144..159 hit zero rows of W_eff
          int dy = (off * 11) >> 5;     // off/3
          int dxx = off - dy * 3;
          short8 a = *(const short8*)(sXH + hbase + (dy * 226 + dxx + c16) * 16 + c0);
#pragma unroll
          for (int nt = 0; nt < 8; ++nt) acc[nt] = MFMA16(a, wf[kc][nt], acc[nt]);
        }
        short* dst = sBUF + (j & 1) * 8704 + wv * 2176;
#pragma unroll
        for (int r = 0; r < 4; ++r) {
          short8 pk;
#pragma unroll
          for (int nt = 0; nt < 8; ++nt) {
            float v = acc[nt][r] + ((nt < 4) ? bA[nt] : bB[nt - 4]);
            pk[nt] = f2bf(fmaxf(v, 0.f));
          }
          *(short8*)(dst + (q * 4 + r) * 136 + c16 * 8) = pk;
        }
      }
      __syncthreads();
    }
  } else {
    // ================= G23 waves: MLP2 + MLP3 + update ===================
    short8 w2f[4][8];                   // 128 VGPR
    short8 w3f[4];                      //  16 VGPR
#pragma unroll
    for (int kc = 0; kc < 4; ++kc)
#pragma unroll
      for (int nt = 0; nt < 8; ++nt)
        w2f[kc][nt] = *(const short8*)(w2g + (nt * 16 + c16) * 136 + kc * 32 + q8);
#pragma unroll
    for (int kc = 0; kc < 4; ++kc)
      w3f[kc] = *(const short8*)(w3g + c16 * 136 + kc * 32 + q8);
    const float4v bA = *(const float4v*)(b2p + c16 * 8);
    const float4v bB = *(const float4v*)(b2p + c16 * 8 + 4);

    const int g = wv - 4;
    short* scr = sH2 + g * 2176;

    __syncthreads();                    // halo ready

    for (int j = 0; j < 15; ++j) {
      if (j >= 1) {
        const int t = 4 * (j - 1) + g;
        const short* src = sBUF + ((j - 1) & 1) * 8704 + g * 2176;
        float4v acc2[8];
#pragma unroll
        for (int nt = 0; nt < 8; ++nt) acc2[nt] = (float4v){0.f, 0.f, 0.f, 0.f};
#pragma unroll
        for (int kc = 0; kc < 4; ++kc) {
          short8 a = *(const short8*)(src + c16 * 136 + kc * 32 + q8);
#pragma unroll
          for (int nt = 0; nt < 8; ++nt) acc2[nt] = MFMA16(a, w2f[kc][nt], acc2[nt]);
        }
#pragma unroll
        for (int r = 0; r < 4; ++r) {
          short8 pk;
#pragma unroll
          for (int nt = 0; nt < 8; ++nt) {
            float v = acc2[nt][r] + ((nt < 4) ? bA[nt] : bB[nt - 4]);
            pk[nt] = f2bf(fmaxf(v, 0.f));
          }
          *(short8*)(scr + (q * 4 + r) * 136 + c16 * 8) = pk;
        }
        float4v acc3 = (float4v){0.f, 0.f, 0.f, 0.f};
#pragma unroll
        for (int kc = 0; kc < 4; ++kc) {
          short8 a = *(const short8*)(scr + c16 * 136 + kc * 32 + q8);
          acc3 = MFMA16(a, w3f[kc], acc3);
        }
        // ---- epilogue: x = clamp(x + dx, 0, 1) ----
        const int rr = t / 14, cb = (t % 14) * 16;
        const int hglob = h0 + rr;
#pragma unroll
        for (int r = 0; r < 4; ++r) {
          int col = cb + q * 4 + r;
          size_t pix = (size_t)(b * 224 + hglob) * 224 + col;
          float v = xs32[pix * 16 + c16] + acc3[r];
          v = fminf(fmaxf(v, 0.f), 1.f);
          if (LAST) {
            dout[((size_t)(b * 16 + c16) * 224 + hglob) * 224 + col] = v;  // NCHW
          } else {
            xd32[pix * 16 + c16] = v;
            xd16[pix * 16 + c16] = f2bf(v);
          }
        }
      }
      __syncthreads();
    }
  }
}

// ---------------------------------------------------------------------------
extern "C" void kernel_launch(void* const* d_in, const int* in_sizes, int n_in,
                              void* d_out, int out_size, void* d_ws, size_t ws_size,
                              hipStream_t stream) {
  const float* x  = (const float*)d_in[0];
  const float* wp = (const float*)d_in[1];
  const float* w1 = (const float*)d_in[2];
  const float* b1 = (const float*)d_in[3];
  const float* w2 = (const float*)d_in[4];
  const float* b2 = (const float*)d_in[5];
  const float* w3 = (const float*)d_in[6];

  char* ws = (char*)d_ws;
  short* wEg = (short*)(ws + WS_WE);
  short* w2g = (short*)(ws + WS_W2);
  short* w3g = (short*)(ws + WS_W3);
  float* b1p = (float*)(ws + WS_B1);
  float* b2p = (float*)(ws + WS_B2);
  float* X32[2] = {(float*)(ws + WS_X32A), (float*)(ws + WS_X32B)};
  short* X16[2] = {(short*)(ws + WS_X16A), (short*)(ws + WS_X16B)};

  prep_x<<<12544, 256, 0, stream>>>(x, X32[0], X16[0]);
  prep_w<<<163, 256, 0, stream>>>(wp, w1, b1, w2, b2, w3, wEg, w2g, w3g, b1p, b2p);

  for (int s = 0; s < 39; ++s) {
    int sb = s & 1;
    ca_step<false><<<224, 512, 0, stream>>>(wEg, w2g, w3g, b1p, b2p,
                                            X32[sb], X16[sb],
                                            X32[1 - sb], X16[1 - sb], nullptr);
  }
  ca_step<true><<<224, 512, 0, stream>>>(wEg, w2g, w3g, b1p, b2p,
                                         X32[1], X16[1],
                                         X32[0], X16[0], (float*)d_out);
}

// Round 3
// 1117.627 us; speedup vs baseline: 1.5570x; 1.0257x over previous
//
#include <hip/hip_runtime.h>

// ---------------------------------------------------------------------------
// NeuralCA fused step, wave-specialized + 3-stage pipeline:
//   waves 0-3 (G1):  h1 = relu(W_eff * im2col(x) + b1)   W_eff regs (160 VGPR)
//   waves 4-7:       iter j: G2 on h1[j-1] -> h2 dbuf;  G3+epilogue on h2[j-2]
//   x = clamp(x + dx, 0, 1)
// h1 via double-buffered LDS mailbox; loop barrier = lgkmcnt(0)+s_barrier only
// (no vmcnt drain - global stores fly free). xs32 residual prefetched an
// iteration's worth of MFMA ahead of use.
// ---------------------------------------------------------------------------

typedef __attribute__((ext_vector_type(8))) short short8;
typedef __attribute__((ext_vector_type(4))) float float4v;

#define MFMA16(a, b, c) __builtin_amdgcn_mfma_f32_16x16x32_bf16((a), (b), (c), 0, 0, 0)

__device__ __forceinline__ short f2bf(float f) {
  unsigned u = __builtin_bit_cast(unsigned, f);
  return (short)((u + 0x8000u) >> 16);     // round-half-up
}

__device__ __forceinline__ void async16(const void* g, void* l) {
  __builtin_amdgcn_global_load_lds((const __attribute__((address_space(1))) void*)g,
                                   (__attribute__((address_space(3))) void*)l,
                                   16, 0, 0);
}

// CK-style LDS-only barrier: no vmcnt drain (stores/loads in flight stay so)
__device__ __forceinline__ void sync_lds() {
  asm volatile("s_waitcnt lgkmcnt(0)\n\ts_barrier" ::: "memory");
}

// ---- workspace layout (bytes) ----
#define WS_WE    0          // W_eff^T [128][168] bf16 (K pad 144->168, zeros)
#define WS_W2    43008      // W2^T    [128][136] bf16 (K sigma-permuted)
#define WS_W3    77824      // W3^T    [ 16][136] bf16 (sigma-perm, pad to 2560)
#define WS_B1    82944      // b1 sigma-permuted f32 [128]
#define WS_B2    83456      // b2 sigma-permuted f32 [128]
#define WS_X32A  83968
#define WS_X32B  12929024
#define WS_X16A  25774080
#define WS_X16B  32196608

// ---------------------------------------------------------------------------
__global__ void prep_x(const float* __restrict__ x, float* __restrict__ x32,
                       short* __restrict__ x16) {
  int i = blockIdx.x * 256 + threadIdx.x;          // exactly 3211264 threads
  int w = i % 224;
  int h = (i / 224) % 224;
  int c = (i / 50176) & 15;
  int bb = i / 802816;
  float v = x[i];
  int o = ((bb * 224 + h) * 224 + w) * 16 + c;     // NHWC
  x32[o] = v;
  x16[o] = f2bf(v);
}

// sigma: stored position p holds channel chan(p) = 16*(p&7) + (p>>3)
__global__ void prep_w(const float* __restrict__ wp, const float* __restrict__ w1,
                       const float* __restrict__ b1, const float* __restrict__ w2,
                       const float* __restrict__ b2, const float* __restrict__ w3,
                       short* __restrict__ wE, short* __restrict__ w2t,
                       short* __restrict__ w3t, float* __restrict__ b1p,
                       float* __restrict__ b2p) {
  int i = blockIdx.x * 256 + threadIdx.x;          // exactly 41728 threads
  if (i < 21504) {                                  // W_eff^T [o=128][k=168]
    int o = i / 168, k = i % 168;
    float v = 0.f;
    if (k < 144) {
      int off = k >> 4, c = k & 15;                 // k = offset*16 + c
      for (int c3 = 0; c3 < 48; ++c3)
        v += w1[o * 48 + c3] * wp[c3 * 144 + c * 9 + off];
    }
    wE[i] = f2bf(v);
  } else if (i < 38912) {                           // W2^T perm [n=128][kk=136]
    int j = i - 21504;
    int n = j / 136, kk = j % 136;
    float v = 0.f;
    if (kk < 128) { int ch = 16 * (kk & 7) + (kk >> 3); v = w2[n * 128 + ch]; }
    w2t[j] = f2bf(v);
  } else if (i < 41472) {                           // W3^T perm, padded to 2560
    int j = i - 38912;
    float v = 0.f;
    if (j < 2176) {
      int n = j / 136, kk = j % 136;
      if (kk < 128) { int ch = 16 * (kk & 7) + (kk >> 3); v = w3[n * 128 + ch]; }
    }
    w3t[j] = f2bf(v);
  } else if (i < 41600) {
    int p = i - 41472;
    b1p[p] = b1[16 * (p & 7) + (p >> 3)];
  } else {
    int p = i - 41600;
    b2p[p] = b2[16 * (p & 7) + (p >> 3)];
  }
}

// ---------------------------------------------------------------------------
// One CA step. Block = 4 image rows of one batch, 512 threads = 8 waves.
// 56 M-tiles (16 px each); pipeline over 16 iterations:
//   G1 wave w:  iter j (<14)  : h1 of tile 4j+w     -> mailbox slot j&1
//   G23 wave g: iter j (1..14): G2 of tile 4(j-1)+g -> h2 dbuf slot j&1
//               iter j (2..15): G3+epilogue of tile 4(j-2)+g from slot (j-1)&1
template <bool LAST>
__global__ __launch_bounds__(512, 2) void ca_step(
    const short* __restrict__ wEg, const short* __restrict__ w2g,
    const short* __restrict__ w3g, const float* __restrict__ b1p,
    const float* __restrict__ b2p, const float* __restrict__ xs32,
    const short* __restrict__ xs16, float* __restrict__ xd32,
    short* __restrict__ xd16, float* __restrict__ dout) {
  __shared__ short sXH[6 * 3616];       // 43392 B  halo: 6 rows x 226 x 16ch
  __shared__ short sBUF[2 * 4 * 2176];  // 34816 B  h1 mailbox, dbuf x 4 slots
  __shared__ short sH2[2 * 4 * 2176];   // 34816 B  per-wave h2 double buffer
  // total 113024 B -> 1 block/CU, 8 waves = 2/SIMD

  const int tid = threadIdx.x;
  const int lane = tid & 63;
  const int wv = tid >> 6;
  const int c16 = lane & 15;
  const int q = lane >> 4;
  const int q8 = q * 8;
  const int qh = q >> 1;
  const int c0 = (q & 1) * 8;

  const int blk = blockIdx.x;           // 224 blocks = 4 batches x 56 rowgroups
  const int b = blk / 56;
  const int h0 = (blk % 56) * 4;

  // ---- stage halo: 6 rows x 7 chunks (1KB each); OOB rows -> zeros ----
  const short8 z8 = {0, 0, 0, 0, 0, 0, 0, 0};
  for (int t = wv; t < 42; t += 8) {
    int hr = t / 7, ck = t % 7;
    int hh = h0 - 1 + hr;
    char* l = (char*)sXH + hr * 7232 + 32 + ck * 1024;  // col 0 = image col -1
    if (hh >= 0 && hh < 224) {
      const char* g = (const char*)xs16 + ((size_t)(b * 224 + hh) * 224) * 32 + ck * 1024;
      async16(g + lane * 16, l);
    } else {
      *(short8*)(l + lane * 16) = z8;
    }
  }
  if (tid < 24) {   // zero edge columns (image col -1 and 224) for all 6 rows
    int hr = tid >> 2, wch = tid & 3;
    int colb = (wch < 2) ? 0 : 225;
    *(short8*)((char*)sXH + hr * 7232 + colb * 32 + (wch & 1) * 16) = z8;
  }

  if (wv < 4) {
    // ================= G1 waves: conv3x3+MLP1 fused ======================
    short8 wf[5][8];                    // 160 VGPR: W_eff fragments
#pragma unroll
    for (int kc = 0; kc < 5; ++kc)
#pragma unroll
      for (int nt = 0; nt < 8; ++nt)
        wf[kc][nt] = *(const short8*)(wEg + (nt * 16 + c16) * 168 + kc * 32 + q8);
    const float4v bA = *(const float4v*)(b1p + c16 * 8);
    const float4v bB = *(const float4v*)(b1p + c16 * 8 + 4);

    __syncthreads();                    // halo ready (drains vmcnt)

    for (int j = 0; j < 16; ++j) {
      if (j < 14) {
        const int t = 4 * j + wv;
        const int rr = t / 14, cb = (t % 14) * 16;
        const int hbase = (rr * 226 + cb) * 16;
        float4v acc[8];
#pragma unroll
        for (int nt = 0; nt < 8; ++nt) acc[nt] = (float4v){0.f, 0.f, 0.f, 0.f};
#pragma unroll
        for (int kc = 0; kc < 5; ++kc) {
          int off = kc * 2 + qh;
          if (off > 8) off = 8;         // K 144..159 hit zero rows of W_eff
          int dy = (off * 11) >> 5;     // off/3
          int dxx = off - dy * 3;
          short8 a = *(const short8*)(sXH + hbase + (dy * 226 + dxx + c16) * 16 + c0);
#pragma unroll
          for (int nt = 0; nt < 8; ++nt) acc[nt] = MFMA16(a, wf[kc][nt], acc[nt]);
        }
        short* dst = sBUF + (j & 1) * 8704 + wv * 2176;
#pragma unroll
        for (int r = 0; r < 4; ++r) {
          short8 pk;
#pragma unroll
          for (int nt = 0; nt < 8; ++nt) {
            float v = acc[nt][r] + ((nt < 4) ? bA[nt] : bB[nt - 4]);
            pk[nt] = f2bf(fmaxf(v, 0.f));
          }
          *(short8*)(dst + (q * 4 + r) * 136 + c16 * 8) = pk;
        }
      }
      sync_lds();
    }
  } else {
    // ========= G23 waves: MLP2 (iter j) + MLP3/update (iter j, tile j-2) ==
    short8 w2f[4][8];                   // 128 VGPR
    short8 w3f[4];                      //  16 VGPR
#pragma unroll
    for (int kc = 0; kc < 4; ++kc)
#pragma unroll
      for (int nt = 0; nt < 8; ++nt)
        w2f[kc][nt] = *(const short8*)(w2g + (nt * 16 + c16) * 136 + kc * 32 + q8);
#pragma unroll
    for (int kc = 0; kc < 4; ++kc)
      w3f[kc] = *(const short8*)(w3g + c16 * 136 + kc * 32 + q8);
    const float4v bA = *(const float4v*)(b2p + c16 * 8);
    const float4v bB = *(const float4v*)(b2p + c16 * 8 + 4);

    const int g = wv - 4;

    __syncthreads();                    // halo ready

    for (int j = 0; j < 16; ++j) {
      // ---- prefetch residual x for the tile G3 finishes this iter ----
      float xres[4];
      int rr3 = 0, cb3 = 0, hglob3 = 0;
      if (j >= 2) {
        const int t3 = 4 * (j - 2) + g;
        rr3 = t3 / 14; cb3 = (t3 % 14) * 16; hglob3 = h0 + rr3;
#pragma unroll
        for (int r = 0; r < 4; ++r) {
          size_t pix = (size_t)(b * 224 + hglob3) * 224 + cb3 + q * 4 + r;
          xres[r] = xs32[pix * 16 + c16];
        }
      }
      // ---- G2: consume h1 mailbox -> h2 dbuf (private, no barrier) ----
      if (j >= 1 && j <= 14) {
        const short* src = sBUF + ((j - 1) & 1) * 8704 + g * 2176;
        float4v acc2[8];
#pragma unroll
        for (int nt = 0; nt < 8; ++nt) acc2[nt] = (float4v){0.f, 0.f, 0.f, 0.f};
#pragma unroll
        for (int kc = 0; kc < 4; ++kc) {
          short8 a = *(const short8*)(src + c16 * 136 + kc * 32 + q8);
#pragma unroll
          for (int nt = 0; nt < 8; ++nt) acc2[nt] = MFMA16(a, w2f[kc][nt], acc2[nt]);
        }
        short* dsth2 = sH2 + ((j & 1) * 4 + g) * 2176;
#pragma unroll
        for (int r = 0; r < 4; ++r) {
          short8 pk;
#pragma unroll
          for (int nt = 0; nt < 8; ++nt) {
            float v = acc2[nt][r] + ((nt < 4) ? bA[nt] : bB[nt - 4]);
            pk[nt] = f2bf(fmaxf(v, 0.f));
          }
          *(short8*)(dsth2 + (q * 4 + r) * 136 + c16 * 8) = pk;
        }
      }
      // ---- G3 + epilogue on h2 written LAST iter (slot (j-1)&1) ----
      if (j >= 2) {
        const short* srch2 = sH2 + (((j - 1) & 1) * 4 + g) * 2176;
        float4v acc3 = (float4v){0.f, 0.f, 0.f, 0.f};
#pragma unroll
        for (int kc = 0; kc < 4; ++kc) {
          short8 a = *(const short8*)(srch2 + c16 * 136 + kc * 32 + q8);
          acc3 = MFMA16(a, w3f[kc], acc3);
        }
#pragma unroll
        for (int r = 0; r < 4; ++r) {
          int col = cb3 + q * 4 + r;
          size_t pix = (size_t)(b * 224 + hglob3) * 224 + col;
          float v = xres[r] + acc3[r];
          v = fminf(fmaxf(v, 0.f), 1.f);
          if (LAST) {
            dout[((size_t)(b * 16 + c16) * 224 + hglob3) * 224 + col] = v;  // NCHW
          } else {
            xd32[pix * 16 + c16] = v;
            xd16[pix * 16 + c16] = f2bf(v);
          }
        }
      }
      sync_lds();
    }
  }
}

// ---------------------------------------------------------------------------
extern "C" void kernel_launch(void* const* d_in, const int* in_sizes, int n_in,
                              void* d_out, int out_size, void* d_ws, size_t ws_size,
                              hipStream_t stream) {
  const float* x  = (const float*)d_in[0];
  const float* wp = (const float*)d_in[1];
  const float* w1 = (const float*)d_in[2];
  const float* b1 = (const float*)d_in[3];
  const float* w2 = (const float*)d_in[4];
  const float* b2 = (const float*)d_in[5];
  const float* w3 = (const float*)d_in[6];

  char* ws = (char*)d_ws;
  short* wEg = (short*)(ws + WS_WE);
  short* w2g = (short*)(ws + WS_W2);
  short* w3g = (short*)(ws + WS_W3);
  float* b1p = (float*)(ws + WS_B1);
  float* b2p = (float*)(ws + WS_B2);
  float* X32[2] = {(float*)(ws + WS_X32A), (float*)(ws + WS_X32B)};
  short* X16[2] = {(short*)(ws + WS_X16A), (short*)(ws + WS_X16B)};

  prep_x<<<12544, 256, 0, stream>>>(x, X32[0], X16[0]);
  prep_w<<<163, 256, 0, stream>>>(wp, w1, b1, w2, b2, w3, wEg, w2g, w3g, b1p, b2p);

  for (int s = 0; s < 39; ++s) {
    int sb = s & 1;
    ca_step<false><<<224, 512, 0, stream>>>(wEg, w2g, w3g, b1p, b2p,
                                            X32[sb], X16[sb],
                                            X32[1 - sb], X16[1 - sb], nullptr);
  }
  ca_step<true><<<224, 512, 0, stream>>>(wEg, w2g, w3g, b1p, b2p,
                                         X32[1], X16[1],
                                         X32[0], X16[0], (float*)d_out);
}